// Round 2
// baseline (23.890 us; speedup 1.0000x reference)
//
#include <hip/hip_runtime.h>
#include <climits>

#define HH 512
#define WW 512
#define HWPIX (HH * WW)
#define BLOCKS_PER_BATCH 64
#define NTHREADS 256

struct Partial {
    int   pa, va;        // plaque / vessel pixel counts
    float pc, vc;        // conf-weighted sums
    int   rmin, rmax, cmin, cmax;  // plaque bbox
};

__global__ __launch_bounds__(NTHREADS)
void mfe_reduce(const float* __restrict__ in, Partial* __restrict__ part) {
    const int b   = blockIdx.y;
    const int k   = blockIdx.x;
    const int tid = threadIdx.x;

    const float4* p0 = (const float4*)(in + (size_t)b * 3 * HWPIX);
    const float4* p1 = p0 + (HWPIX / 4);
    const float4* p2 = p0 + 2 * (HWPIX / 4);

    int   pa = 0, va = 0;
    float pc = 0.f, vc = 0.f;
    int   rmin = INT_MAX, rmax = -1, cmin = INT_MAX, cmax = -1;

    const int ngroups = HWPIX / 4;  // 65536 float4-groups per batch
    for (int g = k * NTHREADS + tid; g < ngroups; g += BLOCKS_PER_BATCH * NTHREADS) {
        float4 a = p0[g];
        float4 v1 = p1[g];
        float4 v2 = p2[g];
        const int row     = g >> 7;            // (4*g) / 512
        const int colbase = (g & 127) << 2;    // (4*g) % 512
        #pragma unroll
        for (int j = 0; j < 4; ++j) {
            float l0 = ((const float*)&a)[j];
            float l1 = ((const float*)&v1)[j];
            float l2 = ((const float*)&v2)[j];
            int pred = 0;
            float m = l0;
            if (l1 > m) { m = l1; pred = 1; }
            if (l2 > m) { m = l2; pred = 2; }
            // softmax prob of the argmax channel: exp(m-m)=1 in numerator
            float s    = __expf(l0 - m) + __expf(l1 - m) + __expf(l2 - m);
            float conf = 1.0f / s;
            if (pred == 1) {
                pa++; pc += conf;
                int col = colbase + j;
                rmin = min(rmin, row); rmax = max(rmax, row);
                cmin = min(cmin, col); cmax = max(cmax, col);
            } else if (pred == 2) {
                va++; vc += conf;
            }
        }
    }

    // wave (64-lane) shuffle reduce
    for (int off = 32; off > 0; off >>= 1) {
        pa += __shfl_down(pa, off, 64);
        va += __shfl_down(va, off, 64);
        pc += __shfl_down(pc, off, 64);
        vc += __shfl_down(vc, off, 64);
        rmin = min(rmin, __shfl_down(rmin, off, 64));
        rmax = max(rmax, __shfl_down(rmax, off, 64));
        cmin = min(cmin, __shfl_down(cmin, off, 64));
        cmax = max(cmax, __shfl_down(cmax, off, 64));
    }

    __shared__ Partial sp[NTHREADS / 64];
    const int wid = tid >> 6;
    if ((tid & 63) == 0) {
        Partial p{pa, va, pc, vc, rmin, rmax, cmin, cmax};
        sp[wid] = p;
    }
    __syncthreads();
    if (tid == 0) {
        Partial r = sp[0];
        #pragma unroll
        for (int w = 1; w < NTHREADS / 64; ++w) {
            r.pa += sp[w].pa;  r.va += sp[w].va;
            r.pc += sp[w].pc;  r.vc += sp[w].vc;
            r.rmin = min(r.rmin, sp[w].rmin);
            r.rmax = max(r.rmax, sp[w].rmax);
            r.cmin = min(r.cmin, sp[w].cmin);
            r.cmax = max(r.cmax, sp[w].cmax);
        }
        part[b * BLOCKS_PER_BATCH + k] = r;
    }
}

__global__ __launch_bounds__(64)
void mfe_finalize(const Partial* __restrict__ part, float* __restrict__ out) {
    const int b    = blockIdx.x;
    const int lane = threadIdx.x;
    Partial r = part[b * BLOCKS_PER_BATCH + lane];

    for (int off = 32; off > 0; off >>= 1) {
        r.pa += __shfl_down(r.pa, off, 64);
        r.va += __shfl_down(r.va, off, 64);
        r.pc += __shfl_down(r.pc, off, 64);
        r.vc += __shfl_down(r.vc, off, 64);
        r.rmin = min(r.rmin, __shfl_down(r.rmin, off, 64));
        r.rmax = max(r.rmax, __shfl_down(r.rmax, off, 64));
        r.cmin = min(r.cmin, __shfl_down(r.cmin, off, 64));
        r.cmax = max(r.cmax, __shfl_down(r.cmax, off, 64));
    }

    if (lane == 0) {
        const float pa = (float)r.pa;
        const float va = (float)r.va;
        const float fa = pa + va;                 // fg = pred>0 = plaque + vessel
        const bool  nonempty = (r.rmax >= 0);
        const float h_range = nonempty ? (float)(r.rmax - r.rmin) : 0.f;
        const float w_range = nonempty ? (float)(r.cmax - r.cmin) : 0.f;
        float* o = out + b * 10;
        o[0] = pa / (va + 1e-6f);                       // plaque_ratio
        o[1] = pa / (fa + 1e-6f);                       // plaque_ratio_fg
        o[2] = r.pc;                                    // plaque_conf_weighted
        o[3] = h_range / (float)HH;                     // h_range / H
        o[4] = w_range / (float)WW;                     // w_range / W
        o[5] = 2.0f * (h_range + w_range) / (float)(HH + WW); // perimeter/(H+W)
        o[6] = r.vc;                                    // vessel_conf_weighted
        o[7] = (r.pa > 0) ? (r.pc / (pa + 1e-6f)) : 0.f;// mean_plaque_conf
        o[8] = fa / (float)HWPIX;                       // fg_area / (H*W)
        o[9] = pa / (float)HWPIX;                       // plaque_area / (H*W)
    }
}

extern "C" void kernel_launch(void* const* d_in, const int* in_sizes, int n_in,
                              void* d_out, int out_size, void* d_ws, size_t ws_size,
                              hipStream_t stream) {
    const float* in  = (const float*)d_in[0];
    float*       out = (float*)d_out;
    Partial*     part = (Partial*)d_ws;

    dim3 grid(BLOCKS_PER_BATCH, 32);
    mfe_reduce<<<grid, NTHREADS, 0, stream>>>(in, part);
    mfe_finalize<<<32, 64, 0, stream>>>(part, out);
}